// Round 13
// baseline (96.303 us; speedup 1.0000x reference)
//
#include <hip/hip_runtime.h>
#include <math.h>

typedef short bf16x8 __attribute__((ext_vector_type(8)));
typedef float f32x4  __attribute__((ext_vector_type(4)));

constexpr int   B_    = 4;
constexpr int   N_    = 2048;
constexpr int   INF_  = 256;
constexpr int   OUTF_ = 128;
constexpr float LAMBDA_INIT_ = 0.35550906759096926f;
constexpr float OUT_SCALE_   = 0.64449093240903074f;   // 1 - LAMBDA_INIT
constexpr float EPS_         = 1e-5f;
constexpr float LOG2E_       = 1.44269504088896340736f;

__device__ inline unsigned short f2bf(float x) {
  unsigned u = __float_as_uint(x);
  u += 0x7fffu + ((u >> 16) & 1u);          // round-to-nearest-even
  return (unsigned short)(u >> 16);
}
__device__ inline unsigned pack2(float a, float b) {
  return (unsigned)f2bf(a) | ((unsigned)f2bf(b) << 16);
}

// ---------------- Kernel A: tiny scalars (rel scores + lambda), log2e-scaled ----------------
__global__ void scalars_kernel(const float* __restrict__ rel_emb,
                               const float* __restrict__ a_rel_pos,
                               const float* __restrict__ a_rel_neg,
                               const float* __restrict__ ll1, const float* __restrict__ lr1,
                               const float* __restrict__ ll2, const float* __restrict__ lr2,
                               float* __restrict__ scal) {
  int lane = threadIdx.x;  // 64 threads, 1 wave
  float p1 = ll1[lane] * lr1[lane];
  float p2 = ll2[lane] * lr2[lane];
  #pragma unroll
  for (int off = 32; off; off >>= 1) { p1 += __shfl_xor(p1, off); p2 += __shfl_xor(p2, off); }
  if (lane == 0) scal[12] = expf(p1) - expf(p2) + LAMBDA_INIT_;   // lam: NOT scaled
  if (lane < 6) {
    float sp = 0.f, sn = 0.f;
    for (int k = 0; k < 10; ++k) {
      float rv = rel_emb[lane * 10 + k];
      sp += rv * a_rel_pos[k];
      sn += rv * a_rel_neg[k];
    }
    scal[lane]     = sp * LOG2E_;
    scal[6 + lane] = sn * LOG2E_;
  }
}

// ---------------- Kernel B: Wh GEMM -> bf16 transposed copy + fused dots ----------------
// 512 blocks x 256 threads; 16 rows x 128 ch. fp32 Wh store DROPPED (dead since r12:
// only WhvT and the dot scores are consumed downstream).
__global__ __launch_bounds__(256) void wh_dots_kernel(
    const float* __restrict__ h, const float* __restrict__ W,
    const float* __restrict__ alp, const float* __restrict__ arp,
    const float* __restrict__ aln, const float* __restrict__ arn,
    unsigned short* __restrict__ WhvT,
    float* __restrict__ lposv, float* __restrict__ rposv,
    float* __restrict__ lnegv, float* __restrict__ rnegv) {
  __shared__ __align__(16) float hT[INF_][20];
  const int t = threadIdx.x;
  const size_t row0 = (size_t)blockIdx.x * 16;
  #pragma unroll
  for (int i = 0; i < 16; ++i) hT[t][i] = h[(row0 + i) * INF_ + t];
  __syncthreads();
  const int c  = t & 127;
  const int rg = t >> 7;
  float acc[8] = {0.f, 0.f, 0.f, 0.f, 0.f, 0.f, 0.f, 0.f};
  #pragma unroll 4
  for (int k = 0; k < INF_; ++k) {
    float wv = W[k * OUTF_ + c];
    const float4* hp = reinterpret_cast<const float4*>(&hT[k][rg * 8]);
    float4 h0 = hp[0], h1 = hp[1];
    acc[0] += h0.x * wv; acc[1] += h0.y * wv; acc[2] += h0.z * wv; acc[3] += h0.w * wv;
    acc[4] += h1.x * wv; acc[5] += h1.y * wv; acc[6] += h1.z * wv; acc[7] += h1.w * wv;
  }
  uint4 pk;
  pk.x = pack2(acc[0], acc[1]); pk.y = pack2(acc[2], acc[3]);
  pk.z = pack2(acc[4], acc[5]); pk.w = pack2(acc[6], acc[7]);
  const int b  = (int)(row0 >> 11);
  const int n0 = (int)(row0 & 2047) + rg * 8;
  *reinterpret_cast<uint4*>(WhvT + ((size_t)b * OUTF_ + c) * N_ + n0) = pk;

  // ---- fused dots: wave wv covers channels (wv&1)*64..+63 of rows rg*8..rg*8+7
  const int lane = t & 63;
  const int wv   = t >> 6;
  const bool pos = (wv & 1) == 0;      // even wave: ch 0..63 (pos half); odd: 64..127 (neg)
  const float al = pos ? alp[lane] : aln[lane];
  const float ar = pos ? arp[lane] : arn[lane];
  float sl[8], sr2[8];
  #pragma unroll
  for (int r = 0; r < 8; ++r) { sl[r] = acc[r] * al; sr2[r] = acc[r] * ar; }
  #pragma unroll
  for (int off = 32; off; off >>= 1) {
    #pragma unroll
    for (int r = 0; r < 8; ++r) {
      sl[r]  += __shfl_xor(sl[r],  off);
      sr2[r] += __shfl_xor(sr2[r], off);
    }
  }
  if (lane == 0) {
    #pragma unroll
    for (int r = 0; r < 8; ++r) {
      const int node = (int)row0 + rg * 8 + r;
      if (pos) { lposv[node] = sl[r] * LOG2E_; rposv[node] = sr2[r] * LOG2E_; }
      else     { lnegv[node] = sl[r] * LOG2E_; rnegv[node] = sr2[r] * LOG2E_; }
    }
  }
}

// ---------------- Kernel D1: attention rows, 4 j's/thread (r12-passing, unchanged) ----------------
__global__ __launch_bounds__(512) void attn_v3d(
    const int* __restrict__ adj,
    const float* __restrict__ lposv, const float* __restrict__ rposv,
    const float* __restrict__ lnegv, const float* __restrict__ rnegv,
    const float* __restrict__ scal, float* __restrict__ out1) {
  __shared__ float sums[16];   // [P:0..7 | N:8..15] per wave
  const int t = threadIdx.x;
  const int lane = t & 63;
  const int wv = t >> 6;
  const int flat = blockIdx.x;        // b*N + i
  const int b = flat >> 11;

  const float lam = scal[12];
  float srcP = -1.0e30f, srcN = -1.0e30f;
  if (lane >= 1 && lane <= 5) { srcP = scal[lane]; srcN = scal[6 + lane]; }
  const int iSrcP = __float_as_int(srcP);
  const int iSrcN = __float_as_int(srcN);

  const float lP = lposv[flat];
  const float lN = lnegv[flat];
  const int j0 = t * 4;
  int4   av4 = *reinterpret_cast<const int4*>(adj + (size_t)flat * N_ + j0);
  float4 rp4 = *reinterpret_cast<const float4*>(rposv + b * N_ + j0);
  float4 rn4 = *reinterpret_cast<const float4*>(rnegv + b * N_ + j0);
  int   av[4] = {av4.x, av4.y, av4.z, av4.w};
  float rp[4] = {rp4.x, rp4.y, rp4.z, rp4.w};
  float rn[4] = {rn4.x, rn4.y, rn4.z, rn4.w};

  float p[4], n[4];
  #pragma unroll
  for (int q = 0; q < 4; ++q) {
    float rsp = __int_as_float(__builtin_amdgcn_ds_bpermute(av[q] << 2, iSrcP));
    float rsn = __int_as_float(__builtin_amdgcn_ds_bpermute(av[q] << 2, iSrcN));
    float e  = lP + rp[q] + rsp;
    float en = lN + rn[q] + rsn;
    e  = fmaxf(e, 0.2f * e);                 // leaky (pos scale commutes with log2e)
    en = fmaxf(en, 0.2f * en);
    p[q] = __builtin_amdgcn_exp2f(e);
    n[q] = __builtin_amdgcn_exp2f(en);
  }
  float sP = (p[0] + p[1]) + (p[2] + p[3]);
  float sN = (n[0] + n[1]) + (n[2] + n[3]);
  #pragma unroll
  for (int off = 32; off; off >>= 1) { sP += __shfl_xor(sP, off); sN += __shfl_xor(sN, off); }
  if (lane == 0) { sums[wv] = sP; sums[8 + wv] = sN; }
  __syncthreads();
  float vP = sums[lane & 7];
  vP += __shfl_xor(vP, 1); vP += __shfl_xor(vP, 2); vP += __shfl_xor(vP, 4);
  float vN = sums[8 + (lane & 7)];
  vN += __shfl_xor(vN, 1); vN += __shfl_xor(vN, 2); vN += __shfl_xor(vN, 4);
  const float s1 = 1.f / vP;
  const float s2 = -lam / vN;

  float a[4];
  #pragma unroll
  for (int q = 0; q < 4; ++q) a[q] = p[q] * s1 + n[q] * s2;
  float* o1 = out1 + (size_t)flat * N_ + j0;
  *reinterpret_cast<float4*>(o1) = make_float4(a[0], a[1], a[2], a[3]);
}

// ---------------- Kernel D2: PV via MFMA, K-split x2 (pv_v5b pipeline, half-K per block) ----------------
// 1024 blocks x 512 threads. Block: tile = bi>>1 (16 rows x 128 ch), kb = bi&1 (K half).
// 4 chunks of 256 k each; partial C written fp32 to hpart[kb]. Indexing verbatim pv_v5b.
__global__ __launch_bounds__(512) void pv_v7(
    const float* __restrict__ attn, const unsigned short* __restrict__ WhvT,
    float* __restrict__ hpart) {
  __shared__ __align__(16) uint4 A4[2][16 * 32];   // [buf][row*32 + unit(16B)], 16KB
  const int t = threadIdx.x;
  const int lane = t & 63;
  const int w = t >> 6;
  const int bi = blockIdx.x;
  const int tile = bi >> 1;
  const int kb   = bi & 1;
  const int b  = tile >> 7;
  const int i0 = (tile & 127) * 16;

  // ---- staging coords: thread covers row sr, one 16B unit sj (8 bf16 = 8 k's)
  const int sr = t >> 5;
  const int sj = t & 31;
  const float4* src4 = reinterpret_cast<const float4*>(
      attn + ((size_t)(b * N_ + i0 + sr)) * N_ + kb * 1024 + sj * 8);
  const int swz = sr & 7;
  const int ui = sr * 32 + (sj ^ swz);

  // ---- compute coords: wave w owns ch tile [w*16, w*16+16)
  const int bl  = lane & 15;   // A row / B ch within tile
  const int kg  = lane >> 4;   // k-group
  const int ch  = w * 16 + bl;
  const unsigned short* Bp = WhvT + ((size_t)b * OUTF_ + ch) * N_ + kb * 1024 + kg * 8;
  f32x4 acc0 = {0.f, 0.f, 0.f, 0.f};   // even chunks
  f32x4 acc1 = {0.f, 0.f, 0.f, 0.f};   // odd chunks
  const int arow = bl * 32;
  const int aswz = bl & 7;

  // stage chunk 0
  {
    float4 s0 = src4[0], s1 = src4[1];
    uint4 u;
    u.x = pack2(s0.x, s0.y); u.y = pack2(s0.z, s0.w);
    u.z = pack2(s1.x, s1.y); u.w = pack2(s1.z, s1.w);
    A4[0][ui] = u;
  }
  __syncthreads();

  for (int c = 0; c < 4; ++c) {
    const int cur = c & 1;
    float4 s0, s1;
    if (c < 3) {  // issue next chunk's global loads before the MFMA cluster
      const int o = (c + 1) * 64;          // 64 float4 per 256-k chunk
      s0 = src4[o]; s1 = src4[o + 1];
    }
    // compute chunk c
    const unsigned short* bp = Bp + c * 256;
    #pragma unroll
    for (int kk = 0; kk < 8; ++kk) {
      bf16x8 a  = *reinterpret_cast<const bf16x8*>(&A4[cur][arow + ((kk * 4 + kg) ^ aswz)]);
      bf16x8 bv = *reinterpret_cast<const bf16x8*>(bp + kk * 32);
      if (cur == 0) acc0 = __builtin_amdgcn_mfma_f32_16x16x32_bf16(a, bv, acc0, 0, 0, 0);
      else          acc1 = __builtin_amdgcn_mfma_f32_16x16x32_bf16(a, bv, acc1, 0, 0, 0);
    }
    if (c < 3) {
      uint4 u;
      u.x = pack2(s0.x, s0.y); u.y = pack2(s0.z, s0.w);
      u.z = pack2(s1.x, s1.y); u.w = pack2(s1.z, s1.w);
      A4[cur ^ 1][ui] = u;
    }
    __syncthreads();
  }

  // ---- partial-C store: C row = kg*4+q, col = ch
  float* hp = hpart + ((size_t)kb * B_ * N_ + (size_t)(b * N_ + i0)) * OUTF_;
  #pragma unroll
  for (int q = 0; q < 4; ++q) hp[(size_t)(kg * 4 + q) * OUTF_ + ch] = acc0[q] + acc1[q];
}

// ---------------- Kernel E: LN + GELU epilogue (r3's verified 16-lane-group pattern) ----------------
// 512 blocks x 256 threads; block: 16 rows, 16 threads/row, 8 strided channels each.
__global__ __launch_bounds__(256) void ln_gelu_kernel(
    const float* __restrict__ hpart,
    const float* __restrict__ gamma, const float* __restrict__ beta,
    float* __restrict__ out0) {
  const int t = threadIdx.x;
  const int bi = blockIdx.x;
  const int b  = bi >> 7;
  const int i0 = (bi & 127) * 16;
  const int row = t >> 4;
  const int c0  = t & 15;

  const size_t idx0 = ((size_t)(b * N_ + i0 + row)) * OUTF_;
  const float* h0 = hpart + idx0;
  const float* h1 = hpart + (size_t)B_ * N_ * OUTF_ + idx0;

  float v[8], g8[8], bt8[8];
  float s = 0.f, sq = 0.f;
  #pragma unroll
  for (int e = 0; e < 8; ++e) {
    const int ch = c0 + e * 16;
    v[e]  = h0[ch] + h1[ch];
    g8[e] = gamma[ch];
    bt8[e] = beta[ch];
    s += v[e]; sq += v[e] * v[e];
  }
  #pragma unroll
  for (int off = 8; off; off >>= 1) { s += __shfl_xor(s, off); sq += __shfl_xor(sq, off); }
  const float mu  = s  * (1.f / 128.f);
  const float var = sq * (1.f / 128.f) - mu * mu;
  const float inv = rsqrtf(var + EPS_);
  float* orow = out0 + idx0;
  #pragma unroll
  for (int e = 0; e < 8; ++e) {
    float y = (v[e] - mu) * inv * g8[e] + bt8[e];
    y *= OUT_SCALE_;
    orow[c0 + e * 16] = 0.5f * y * (1.f + erff(y * 0.70710678118654752f));
  }
}

extern "C" void kernel_launch(void* const* d_in, const int* in_sizes, int n_in,
                              void* d_out, int out_size, void* d_ws, size_t ws_size,
                              hipStream_t stream) {
  (void)in_sizes; (void)n_in; (void)out_size; (void)ws_size;
  const float* h        = (const float*)d_in[0];
  const int*   adj      = (const int*)d_in[1];
  const float* W        = (const float*)d_in[2];
  const float* alp      = (const float*)d_in[3];
  const float* arp      = (const float*)d_in[4];
  const float* aln      = (const float*)d_in[5];
  const float* arn      = (const float*)d_in[6];
  const float* rel_emb  = (const float*)d_in[7];
  const float* a_rel_p  = (const float*)d_in[8];
  const float* a_rel_n  = (const float*)d_in[9];
  const float* ll1      = (const float*)d_in[10];
  const float* lr1      = (const float*)d_in[11];
  const float* ll2      = (const float*)d_in[12];
  const float* lr2      = (const float*)d_in[13];
  const float* gamma    = (const float*)d_in[14];
  const float* beta     = (const float*)d_in[15];

  float* out0 = (float*)d_out;                          // gelu(h'): B*N*OUTF
  float* out1 = out0 + (size_t)B_ * N_ * OUTF_;         // attention: B*N*N

  float* ws    = (float*)d_ws;
  float* scal  = ws;                    // 32 floats
  float* lposv = ws + 32;               // B*N
  float* rposv = lposv + B_ * N_;
  float* lnegv = rposv + B_ * N_;
  float* rnegv = lnegv + B_ * N_;
  unsigned short* WhvT = (unsigned short*)(rnegv + B_ * N_);            // [B][OUTF][N] bf16
  float* hpart = (float*)(WhvT + (size_t)B_ * N_ * OUTF_);              // [2][B*N][OUTF] fp32

  scalars_kernel<<<1, 64, 0, stream>>>(rel_emb, a_rel_p, a_rel_n, ll1, lr1, ll2, lr2, scal);
  wh_dots_kernel<<<(B_ * N_) / 16, 256, 0, stream>>>(h, W, alp, arp, aln, arn,
                                                     WhvT, lposv, rposv, lnegv, rnegv);
  attn_v3d<<<B_ * N_, 512, 0, stream>>>(adj, lposv, rposv, lnegv, rnegv, scal, out1);
  pv_v7<<<B_ * (N_ / 16) * 2, 512, 0, stream>>>(out1, WhvT, hpart);
  ln_gelu_kernel<<<B_ * (N_ / 16), 256, 0, stream>>>(hpart, gamma, beta, out0);
}

// Round 14
// 91.313 us; speedup vs baseline: 1.0546x; 1.0546x over previous
//
#include <hip/hip_runtime.h>
#include <math.h>

typedef short bf16x8 __attribute__((ext_vector_type(8)));
typedef float f32x4  __attribute__((ext_vector_type(4)));

constexpr int   B_    = 4;
constexpr int   N_    = 2048;
constexpr int   INF_  = 256;
constexpr int   OUTF_ = 128;
constexpr float LAMBDA_INIT_ = 0.35550906759096926f;
constexpr float OUT_SCALE_   = 0.64449093240903074f;   // 1 - LAMBDA_INIT
constexpr float EPS_         = 1e-5f;
constexpr float LOG2E_       = 1.44269504088896340736f;

__device__ inline unsigned short f2bf(float x) {
  unsigned u = __float_as_uint(x);
  u += 0x7fffu + ((u >> 16) & 1u);          // round-to-nearest-even
  return (unsigned short)(u >> 16);
}
__device__ inline unsigned pack2(float a, float b) {
  return (unsigned)f2bf(a) | ((unsigned)f2bf(b) << 16);
}

// ---------------- Kernel A: tiny scalars (rel scores + lambda), log2e-scaled ----------------
__global__ void scalars_kernel(const float* __restrict__ rel_emb,
                               const float* __restrict__ a_rel_pos,
                               const float* __restrict__ a_rel_neg,
                               const float* __restrict__ ll1, const float* __restrict__ lr1,
                               const float* __restrict__ ll2, const float* __restrict__ lr2,
                               float* __restrict__ scal) {
  int lane = threadIdx.x;  // 64 threads, 1 wave
  float p1 = ll1[lane] * lr1[lane];
  float p2 = ll2[lane] * lr2[lane];
  #pragma unroll
  for (int off = 32; off; off >>= 1) { p1 += __shfl_xor(p1, off); p2 += __shfl_xor(p2, off); }
  if (lane == 0) scal[12] = expf(p1) - expf(p2) + LAMBDA_INIT_;   // lam: NOT scaled
  if (lane < 6) {
    float sp = 0.f, sn = 0.f;
    for (int k = 0; k < 10; ++k) {
      float rv = rel_emb[lane * 10 + k];
      sp += rv * a_rel_pos[k];
      sn += rv * a_rel_neg[k];
    }
    scal[lane]     = sp * LOG2E_;
    scal[6 + lane] = sn * LOG2E_;
  }
}

// ---------------- Kernel B: Wh GEMM -> bf16 transposed copy + fused dots (r12-passing) ----------------
__global__ __launch_bounds__(256) void wh_dots_kernel(
    const float* __restrict__ h, const float* __restrict__ W,
    const float* __restrict__ alp, const float* __restrict__ arp,
    const float* __restrict__ aln, const float* __restrict__ arn,
    unsigned short* __restrict__ WhvT,
    float* __restrict__ lposv, float* __restrict__ rposv,
    float* __restrict__ lnegv, float* __restrict__ rnegv) {
  __shared__ __align__(16) float hT[INF_][20];
  const int t = threadIdx.x;
  const size_t row0 = (size_t)blockIdx.x * 16;
  #pragma unroll
  for (int i = 0; i < 16; ++i) hT[t][i] = h[(row0 + i) * INF_ + t];
  __syncthreads();
  const int c  = t & 127;
  const int rg = t >> 7;
  float acc[8] = {0.f, 0.f, 0.f, 0.f, 0.f, 0.f, 0.f, 0.f};
  #pragma unroll 4
  for (int k = 0; k < INF_; ++k) {
    float wv = W[k * OUTF_ + c];
    const float4* hp = reinterpret_cast<const float4*>(&hT[k][rg * 8]);
    float4 h0 = hp[0], h1 = hp[1];
    acc[0] += h0.x * wv; acc[1] += h0.y * wv; acc[2] += h0.z * wv; acc[3] += h0.w * wv;
    acc[4] += h1.x * wv; acc[5] += h1.y * wv; acc[6] += h1.z * wv; acc[7] += h1.w * wv;
  }
  uint4 pk;
  pk.x = pack2(acc[0], acc[1]); pk.y = pack2(acc[2], acc[3]);
  pk.z = pack2(acc[4], acc[5]); pk.w = pack2(acc[6], acc[7]);
  const int b  = (int)(row0 >> 11);
  const int n0 = (int)(row0 & 2047) + rg * 8;
  *reinterpret_cast<uint4*>(WhvT + ((size_t)b * OUTF_ + c) * N_ + n0) = pk;

  // ---- fused dots: wave wv covers channels (wv&1)*64..+63 of rows rg*8..rg*8+7
  const int lane = t & 63;
  const int wv   = t >> 6;
  const bool pos = (wv & 1) == 0;      // even wave: ch 0..63 (pos half); odd: 64..127 (neg)
  const float al = pos ? alp[lane] : aln[lane];
  const float ar = pos ? arp[lane] : arn[lane];
  float sl[8], sr2[8];
  #pragma unroll
  for (int r = 0; r < 8; ++r) { sl[r] = acc[r] * al; sr2[r] = acc[r] * ar; }
  #pragma unroll
  for (int off = 32; off; off >>= 1) {
    #pragma unroll
    for (int r = 0; r < 8; ++r) {
      sl[r]  += __shfl_xor(sl[r],  off);
      sr2[r] += __shfl_xor(sr2[r], off);
    }
  }
  if (lane == 0) {
    #pragma unroll
    for (int r = 0; r < 8; ++r) {
      const int node = (int)row0 + rg * 8 + r;
      if (pos) { lposv[node] = sl[r] * LOG2E_; rposv[node] = sr2[r] * LOG2E_; }
      else     { lnegv[node] = sl[r] * LOG2E_; rnegv[node] = sr2[r] * LOG2E_; }
    }
  }
}

// ---------------- Kernel D1: attention, 8 rows per block (fixed-cost amortized) ----------------
// 1024 blocks x 512 threads; block owns rows bid*8..bid*8+7 (same batch b).
// Per-row math identical to r12's passing attn_v3d. rposv/rnegv loaded ONCE per block
// (row-invariant); adj prefetched one row ahead; sums double-buffered, 1 barrier/row.
__global__ __launch_bounds__(512) void attn_v4(
    const int* __restrict__ adj,
    const float* __restrict__ lposv, const float* __restrict__ rposv,
    const float* __restrict__ lnegv, const float* __restrict__ rnegv,
    const float* __restrict__ scal, float* __restrict__ out1) {
  __shared__ float sums[2][16];   // [buf][P:0..7 | N:8..15]
  const int t = threadIdx.x;
  const int lane = t & 63;
  const int wv = t >> 6;
  const int flat0 = blockIdx.x * 8;   // b*N + i base
  const int b = flat0 >> 11;

  const float lam = scal[12];
  float srcP = -1.0e30f, srcN = -1.0e30f;
  if (lane >= 1 && lane <= 5) { srcP = scal[lane]; srcN = scal[6 + lane]; }
  const int iSrcP = __float_as_int(srcP);
  const int iSrcN = __float_as_int(srcN);

  const int j0 = t * 4;
  // row-invariant right-score vectors: load once
  float4 rp4 = *reinterpret_cast<const float4*>(rposv + b * N_ + j0);
  float4 rn4 = *reinterpret_cast<const float4*>(rnegv + b * N_ + j0);
  const float rp[4] = {rp4.x, rp4.y, rp4.z, rp4.w};
  const float rn[4] = {rn4.x, rn4.y, rn4.z, rn4.w};

  // prefetch row 0's adj
  int4 avN = *reinterpret_cast<const int4*>(adj + (size_t)flat0 * N_ + j0);

  #pragma unroll
  for (int r = 0; r < 8; ++r) {
    const int flat = flat0 + r;
    const int4 av4 = avN;
    if (r < 7)
      avN = *reinterpret_cast<const int4*>(adj + (size_t)(flat + 1) * N_ + j0);
    const float lP = lposv[flat];
    const float lN = lnegv[flat];
    int av[4] = {av4.x, av4.y, av4.z, av4.w};

    float p[4], n[4];
    #pragma unroll
    for (int q = 0; q < 4; ++q) {
      float rsp = __int_as_float(__builtin_amdgcn_ds_bpermute(av[q] << 2, iSrcP));
      float rsn = __int_as_float(__builtin_amdgcn_ds_bpermute(av[q] << 2, iSrcN));
      float e  = lP + rp[q] + rsp;
      float en = lN + rn[q] + rsn;
      e  = fmaxf(e, 0.2f * e);                 // leaky (pos scale commutes with log2e)
      en = fmaxf(en, 0.2f * en);
      p[q] = __builtin_amdgcn_exp2f(e);
      n[q] = __builtin_amdgcn_exp2f(en);
    }
    float sP = (p[0] + p[1]) + (p[2] + p[3]);
    float sN = (n[0] + n[1]) + (n[2] + n[3]);
    #pragma unroll
    for (int off = 32; off; off >>= 1) { sP += __shfl_xor(sP, off); sN += __shfl_xor(sN, off); }
    const int bf = r & 1;
    if (lane == 0) { sums[bf][wv] = sP; sums[bf][8 + wv] = sN; }
    __syncthreads();
    float vP = sums[bf][lane & 7];
    vP += __shfl_xor(vP, 1); vP += __shfl_xor(vP, 2); vP += __shfl_xor(vP, 4);
    float vN = sums[bf][8 + (lane & 7)];
    vN += __shfl_xor(vN, 1); vN += __shfl_xor(vN, 2); vN += __shfl_xor(vN, 4);
    const float s1 = 1.f / vP;
    const float s2 = -lam / vN;

    float a[4];
    #pragma unroll
    for (int q = 0; q < 4; ++q) a[q] = p[q] * s1 + n[q] * s2;
    float* o1 = out1 + (size_t)flat * N_ + j0;
    *reinterpret_cast<float4*>(o1) = make_float4(a[0], a[1], a[2], a[3]);
  }
}

// ---------------- Kernel D2: PV via MFMA (r12-passing pv_v5b, unchanged) ----------------
__global__ __launch_bounds__(512) void pv_v5b(
    const float* __restrict__ attn, const unsigned short* __restrict__ WhvT,
    const float* __restrict__ gamma, const float* __restrict__ beta,
    float* __restrict__ out0) {
  __shared__ __align__(16) uint4 A4[2][16 * 32];   // [buf][row*32 + unit(16B)], 16KB
  __shared__ __align__(16) float hp[16][132];
  const int t = threadIdx.x;
  const int lane = t & 63;
  const int w = t >> 6;
  const int bi = blockIdx.x;
  const int b  = bi >> 7;
  const int i0 = (bi & 127) * 16;

  const int sr = t >> 5;
  const int sj = t & 31;
  const float4* src4 = reinterpret_cast<const float4*>(
      attn + ((size_t)(b * N_ + i0 + sr)) * N_ + sj * 8);
  const int swz = sr & 7;
  const int ui = sr * 32 + (sj ^ swz);

  const int bl  = lane & 15;   // A row / B ch within tile
  const int kg  = lane >> 4;   // k-group
  const int ch  = w * 16 + bl;
  const unsigned short* Bp = WhvT + ((size_t)b * OUTF_ + ch) * N_ + kg * 8;
  f32x4 acc0 = {0.f, 0.f, 0.f, 0.f};   // even chunks
  f32x4 acc1 = {0.f, 0.f, 0.f, 0.f};   // odd chunks
  const int arow = bl * 32;
  const int aswz = bl & 7;

  {
    float4 s0 = src4[0], s1 = src4[1];
    uint4 u;
    u.x = pack2(s0.x, s0.y); u.y = pack2(s0.z, s0.w);
    u.z = pack2(s1.x, s1.y); u.w = pack2(s1.z, s1.w);
    A4[0][ui] = u;
  }
  __syncthreads();

  for (int c = 0; c < 8; ++c) {
    const int cur = c & 1;
    float4 s0, s1;
    if (c < 7) {
      const int o = (c + 1) * 64;          // 64 float4 per 256-k chunk
      s0 = src4[o]; s1 = src4[o + 1];
    }
    const unsigned short* bp = Bp + c * 256;
    #pragma unroll
    for (int kk = 0; kk < 8; ++kk) {
      bf16x8 a  = *reinterpret_cast<const bf16x8*>(&A4[cur][arow + ((kk * 4 + kg) ^ aswz)]);
      bf16x8 bv = *reinterpret_cast<const bf16x8*>(bp + kk * 32);
      if (cur == 0) acc0 = __builtin_amdgcn_mfma_f32_16x16x32_bf16(a, bv, acc0, 0, 0, 0);
      else          acc1 = __builtin_amdgcn_mfma_f32_16x16x32_bf16(a, bv, acc1, 0, 0, 0);
    }
    if (c < 7) {
      uint4 u;
      u.x = pack2(s0.x, s0.y); u.y = pack2(s0.z, s0.w);
      u.z = pack2(s1.x, s1.y); u.w = pack2(s1.z, s1.w);
      A4[cur ^ 1][ui] = u;
    }
    __syncthreads();
  }

  #pragma unroll
  for (int q = 0; q < 4; ++q) hp[kg * 4 + q][ch] = acc0[q] + acc1[q];
  __syncthreads();

  const int row = t >> 5;
  const int c0  = t & 31;
  float v[4], s = 0.f, sq = 0.f;
  #pragma unroll
  for (int e = 0; e < 4; ++e) {
    v[e] = hp[row][c0 + e * 32];
    s += v[e]; sq += v[e] * v[e];
  }
  #pragma unroll
  for (int off = 16; off; off >>= 1) { s += __shfl_xor(s, off); sq += __shfl_xor(sq, off); }
  const float mu  = s  * (1.f / 128.f);
  const float var = sq * (1.f / 128.f) - mu * mu;
  const float inv = rsqrtf(var + EPS_);
  float* orow = out0 + ((size_t)(b * N_ + i0 + row)) * OUTF_;
  #pragma unroll
  for (int e = 0; e < 4; ++e) {
    const int chh = c0 + e * 32;
    float y = (v[e] - mu) * inv * gamma[chh] + beta[chh];
    y *= OUT_SCALE_;
    orow[chh] = 0.5f * y * (1.f + erff(y * 0.70710678118654752f));
  }
}

extern "C" void kernel_launch(void* const* d_in, const int* in_sizes, int n_in,
                              void* d_out, int out_size, void* d_ws, size_t ws_size,
                              hipStream_t stream) {
  (void)in_sizes; (void)n_in; (void)out_size; (void)ws_size;
  const float* h        = (const float*)d_in[0];
  const int*   adj      = (const int*)d_in[1];
  const float* W        = (const float*)d_in[2];
  const float* alp      = (const float*)d_in[3];
  const float* arp      = (const float*)d_in[4];
  const float* aln      = (const float*)d_in[5];
  const float* arn      = (const float*)d_in[6];
  const float* rel_emb  = (const float*)d_in[7];
  const float* a_rel_p  = (const float*)d_in[8];
  const float* a_rel_n  = (const float*)d_in[9];
  const float* ll1      = (const float*)d_in[10];
  const float* lr1      = (const float*)d_in[11];
  const float* ll2      = (const float*)d_in[12];
  const float* lr2      = (const float*)d_in[13];
  const float* gamma    = (const float*)d_in[14];
  const float* beta     = (const float*)d_in[15];

  float* out0 = (float*)d_out;                          // gelu(h'): B*N*OUTF
  float* out1 = out0 + (size_t)B_ * N_ * OUTF_;         // attention: B*N*N

  float* ws    = (float*)d_ws;
  float* scal  = ws;                    // 32 floats
  float* lposv = ws + 32;               // B*N
  float* rposv = lposv + B_ * N_;
  float* lnegv = rposv + B_ * N_;
  float* rnegv = lnegv + B_ * N_;
  unsigned short* WhvT = (unsigned short*)(rnegv + B_ * N_);   // [B][OUTF][N] bf16

  scalars_kernel<<<1, 64, 0, stream>>>(rel_emb, a_rel_p, a_rel_n, ll1, lr1, ll2, lr2, scal);
  wh_dots_kernel<<<(B_ * N_) / 16, 256, 0, stream>>>(h, W, alp, arp, aln, arn,
                                                     WhvT, lposv, rposv, lnegv, rnegv);
  attn_v4<<<(B_ * N_) / 8, 512, 0, stream>>>(adj, lposv, rposv, lnegv, rnegv, scal, out1);
  pv_v5b<<<B_ * (N_ / 16), 512, 0, stream>>>(out1, WhvT, gamma, beta, out0);
}

// Round 15
// 90.809 us; speedup vs baseline: 1.0605x; 1.0056x over previous
//
#include <hip/hip_runtime.h>
#include <math.h>

typedef short bf16x8 __attribute__((ext_vector_type(8)));
typedef float f32x4  __attribute__((ext_vector_type(4)));

constexpr int   B_    = 4;
constexpr int   N_    = 2048;
constexpr int   INF_  = 256;
constexpr int   OUTF_ = 128;
constexpr float LAMBDA_INIT_ = 0.35550906759096926f;
constexpr float OUT_SCALE_   = 0.64449093240903074f;   // 1 - LAMBDA_INIT
constexpr float EPS_         = 1e-5f;
constexpr float LOG2E_       = 1.44269504088896340736f;

__device__ inline unsigned short f2bf(float x) {
  unsigned u = __float_as_uint(x);
  u += 0x7fffu + ((u >> 16) & 1u);          // round-to-nearest-even
  return (unsigned short)(u >> 16);
}
__device__ inline unsigned pack2(float a, float b) {
  return (unsigned)f2bf(a) | ((unsigned)f2bf(b) << 16);
}

// ---------------- Kernel A: tiny scalars (rel scores + lambda), log2e-scaled ----------------
__global__ void scalars_kernel(const float* __restrict__ rel_emb,
                               const float* __restrict__ a_rel_pos,
                               const float* __restrict__ a_rel_neg,
                               const float* __restrict__ ll1, const float* __restrict__ lr1,
                               const float* __restrict__ ll2, const float* __restrict__ lr2,
                               float* __restrict__ scal) {
  int lane = threadIdx.x;  // 64 threads, 1 wave
  float p1 = ll1[lane] * lr1[lane];
  float p2 = ll2[lane] * lr2[lane];
  #pragma unroll
  for (int off = 32; off; off >>= 1) { p1 += __shfl_xor(p1, off); p2 += __shfl_xor(p2, off); }
  if (lane == 0) scal[12] = expf(p1) - expf(p2) + LAMBDA_INIT_;   // lam: NOT scaled
  if (lane < 6) {
    float sp = 0.f, sn = 0.f;
    for (int k = 0; k < 10; ++k) {
      float rv = rel_emb[lane * 10 + k];
      sp += rv * a_rel_pos[k];
      sn += rv * a_rel_neg[k];
    }
    scal[lane]     = sp * LOG2E_;
    scal[6 + lane] = sn * LOG2E_;
  }
}

// ---------------- Kernel B: Wh GEMM -> bf16 transposed copy + fused dots (r12-passing) ----------------
__global__ __launch_bounds__(256) void wh_dots_kernel(
    const float* __restrict__ h, const float* __restrict__ W,
    const float* __restrict__ alp, const float* __restrict__ arp,
    const float* __restrict__ aln, const float* __restrict__ arn,
    unsigned short* __restrict__ WhvT,
    float* __restrict__ lposv, float* __restrict__ rposv,
    float* __restrict__ lnegv, float* __restrict__ rnegv) {
  __shared__ __align__(16) float hT[INF_][20];
  const int t = threadIdx.x;
  const size_t row0 = (size_t)blockIdx.x * 16;
  #pragma unroll
  for (int i = 0; i < 16; ++i) hT[t][i] = h[(row0 + i) * INF_ + t];
  __syncthreads();
  const int c  = t & 127;
  const int rg = t >> 7;
  float acc[8] = {0.f, 0.f, 0.f, 0.f, 0.f, 0.f, 0.f, 0.f};
  #pragma unroll 4
  for (int k = 0; k < INF_; ++k) {
    float wv = W[k * OUTF_ + c];
    const float4* hp = reinterpret_cast<const float4*>(&hT[k][rg * 8]);
    float4 h0 = hp[0], h1 = hp[1];
    acc[0] += h0.x * wv; acc[1] += h0.y * wv; acc[2] += h0.z * wv; acc[3] += h0.w * wv;
    acc[4] += h1.x * wv; acc[5] += h1.y * wv; acc[6] += h1.z * wv; acc[7] += h1.w * wv;
  }
  uint4 pk;
  pk.x = pack2(acc[0], acc[1]); pk.y = pack2(acc[2], acc[3]);
  pk.z = pack2(acc[4], acc[5]); pk.w = pack2(acc[6], acc[7]);
  const int b  = (int)(row0 >> 11);
  const int n0 = (int)(row0 & 2047) + rg * 8;
  *reinterpret_cast<uint4*>(WhvT + ((size_t)b * OUTF_ + c) * N_ + n0) = pk;

  // ---- fused dots: wave wv covers channels (wv&1)*64..+63 of rows rg*8..rg*8+7
  const int lane = t & 63;
  const int wv   = t >> 6;
  const bool pos = (wv & 1) == 0;      // even wave: ch 0..63 (pos half); odd: 64..127 (neg)
  const float al = pos ? alp[lane] : aln[lane];
  const float ar = pos ? arp[lane] : arn[lane];
  float sl[8], sr2[8];
  #pragma unroll
  for (int r = 0; r < 8; ++r) { sl[r] = acc[r] * al; sr2[r] = acc[r] * ar; }
  #pragma unroll
  for (int off = 32; off; off >>= 1) {
    #pragma unroll
    for (int r = 0; r < 8; ++r) {
      sl[r]  += __shfl_xor(sl[r],  off);
      sr2[r] += __shfl_xor(sr2[r], off);
    }
  }
  if (lane == 0) {
    #pragma unroll
    for (int r = 0; r < 8; ++r) {
      const int node = (int)row0 + rg * 8 + r;
      if (pos) { lposv[node] = sl[r] * LOG2E_; rposv[node] = sr2[r] * LOG2E_; }
      else     { lnegv[node] = sl[r] * LOG2E_; rnegv[node] = sr2[r] * LOG2E_; }
    }
  }
}

// ---------------- Kernel D1: attention, 8 rows per block (r14-passing, unchanged) ----------------
__global__ __launch_bounds__(512) void attn_v4(
    const int* __restrict__ adj,
    const float* __restrict__ lposv, const float* __restrict__ rposv,
    const float* __restrict__ lnegv, const float* __restrict__ rnegv,
    const float* __restrict__ scal, float* __restrict__ out1) {
  __shared__ float sums[2][16];   // [buf][P:0..7 | N:8..15]
  const int t = threadIdx.x;
  const int lane = t & 63;
  const int wv = t >> 6;
  const int flat0 = blockIdx.x * 8;   // b*N + i base
  const int b = flat0 >> 11;

  const float lam = scal[12];
  float srcP = -1.0e30f, srcN = -1.0e30f;
  if (lane >= 1 && lane <= 5) { srcP = scal[lane]; srcN = scal[6 + lane]; }
  const int iSrcP = __float_as_int(srcP);
  const int iSrcN = __float_as_int(srcN);

  const int j0 = t * 4;
  float4 rp4 = *reinterpret_cast<const float4*>(rposv + b * N_ + j0);
  float4 rn4 = *reinterpret_cast<const float4*>(rnegv + b * N_ + j0);
  const float rp[4] = {rp4.x, rp4.y, rp4.z, rp4.w};
  const float rn[4] = {rn4.x, rn4.y, rn4.z, rn4.w};

  int4 avN = *reinterpret_cast<const int4*>(adj + (size_t)flat0 * N_ + j0);

  #pragma unroll
  for (int r = 0; r < 8; ++r) {
    const int flat = flat0 + r;
    const int4 av4 = avN;
    if (r < 7)
      avN = *reinterpret_cast<const int4*>(adj + (size_t)(flat + 1) * N_ + j0);
    const float lP = lposv[flat];
    const float lN = lnegv[flat];
    int av[4] = {av4.x, av4.y, av4.z, av4.w};

    float p[4], n[4];
    #pragma unroll
    for (int q = 0; q < 4; ++q) {
      float rsp = __int_as_float(__builtin_amdgcn_ds_bpermute(av[q] << 2, iSrcP));
      float rsn = __int_as_float(__builtin_amdgcn_ds_bpermute(av[q] << 2, iSrcN));
      float e  = lP + rp[q] + rsp;
      float en = lN + rn[q] + rsn;
      e  = fmaxf(e, 0.2f * e);
      en = fmaxf(en, 0.2f * en);
      p[q] = __builtin_amdgcn_exp2f(e);
      n[q] = __builtin_amdgcn_exp2f(en);
    }
    float sP = (p[0] + p[1]) + (p[2] + p[3]);
    float sN = (n[0] + n[1]) + (n[2] + n[3]);
    #pragma unroll
    for (int off = 32; off; off >>= 1) { sP += __shfl_xor(sP, off); sN += __shfl_xor(sN, off); }
    const int bf = r & 1;
    if (lane == 0) { sums[bf][wv] = sP; sums[bf][8 + wv] = sN; }
    __syncthreads();
    float vP = sums[bf][lane & 7];
    vP += __shfl_xor(vP, 1); vP += __shfl_xor(vP, 2); vP += __shfl_xor(vP, 4);
    float vN = sums[bf][8 + (lane & 7)];
    vN += __shfl_xor(vN, 1); vN += __shfl_xor(vN, 2); vN += __shfl_xor(vN, 4);
    const float s1 = 1.f / vP;
    const float s2 = -lam / vN;

    float a[4];
    #pragma unroll
    for (int q = 0; q < 4; ++q) a[q] = p[q] * s1 + n[q] * s2;
    float* o1 = out1 + (size_t)flat * N_ + j0;
    *reinterpret_cast<float4*>(o1) = make_float4(a[0], a[1], a[2], a[3]);
  }
}

// ---------------- Kernel D2: PV via MFMA, deep prefetch (A depth-2, B depth-1 in regs) ----------------
// 512 blocks x 512 threads (8 waves, one 16-ch tile each, 2 acc chains).
// Same fragment/swizzle/epilogue indexing as the r12-passing pv_v5b; only the
// load schedule changes: A(c+2) issued 2 iters early, B(c+1) register-buffered.
__global__ __launch_bounds__(512, 4) void pv_v5c(
    const float* __restrict__ attn, const unsigned short* __restrict__ WhvT,
    const float* __restrict__ gamma, const float* __restrict__ beta,
    float* __restrict__ out0) {
  __shared__ __align__(16) uint4 A4[2][16 * 32];   // [buf][row*32 + unit(16B)], 16KB
  __shared__ __align__(16) float hp[16][132];
  const int t = threadIdx.x;
  const int lane = t & 63;
  const int w = t >> 6;
  const int bi = blockIdx.x;
  const int b  = bi >> 7;
  const int i0 = (bi & 127) * 16;

  const int sr = t >> 5;
  const int sj = t & 31;
  const float4* src4 = reinterpret_cast<const float4*>(
      attn + ((size_t)(b * N_ + i0 + sr)) * N_ + sj * 8);
  const int swz = sr & 7;
  const int ui = sr * 32 + (sj ^ swz);

  const int bl  = lane & 15;   // A row / B ch within tile
  const int kg  = lane >> 4;   // k-group
  const int ch  = w * 16 + bl;
  const unsigned short* Bp = WhvT + ((size_t)b * OUTF_ + ch) * N_ + kg * 8;
  f32x4 acc0 = {0.f, 0.f, 0.f, 0.f};   // even chunks
  f32x4 acc1 = {0.f, 0.f, 0.f, 0.f};   // odd chunks
  const int arow = bl * 32;
  const int aswz = bl & 7;

  bf16x8 bBuf[2][8];           // parity-indexed B fragments (static indices when unrolled)

  // ---- prologue: stage A(0); issue A(1) into regs; issue B(0) into bBuf[0]
  {
    float4 s0 = src4[0], s1 = src4[1];
    uint4 u;
    u.x = pack2(s0.x, s0.y); u.y = pack2(s0.z, s0.w);
    u.z = pack2(s1.x, s1.y); u.w = pack2(s1.z, s1.w);
    A4[0][ui] = u;
  }
  float4 n0 = src4[64], n1 = src4[65];          // A(1) data in regs
  #pragma unroll
  for (int kk = 0; kk < 8; ++kk)
    bBuf[0][kk] = *reinterpret_cast<const bf16x8*>(Bp + kk * 32);
  __syncthreads();

  #pragma unroll
  for (int c = 0; c < 8; ++c) {
    const int cur = c & 1;
    float4 m0, m1;                               // A(c+2) issue
    if (c < 6) { m0 = src4[(c + 2) * 64]; m1 = src4[(c + 2) * 64 + 1]; }
    if (c < 7) {                                 // B(c+1) issue into other parity
      #pragma unroll
      for (int kk = 0; kk < 8; ++kk)
        bBuf[cur ^ 1][kk] = *reinterpret_cast<const bf16x8*>(Bp + (c + 1) * 256 + kk * 32);
    }
    // MFMA cluster on A4[cur] x bBuf[cur]
    #pragma unroll
    for (int kk = 0; kk < 8; ++kk) {
      bf16x8 a = *reinterpret_cast<const bf16x8*>(&A4[cur][arow + ((kk * 4 + kg) ^ aswz)]);
      if (cur == 0) acc0 = __builtin_amdgcn_mfma_f32_16x16x32_bf16(a, bBuf[0][kk], acc0, 0, 0, 0);
      else          acc1 = __builtin_amdgcn_mfma_f32_16x16x32_bf16(a, bBuf[1][kk], acc1, 0, 0, 0);
    }
    if (c < 7) {                                 // write A(c+1) (issued last iter) to LDS
      uint4 u;
      u.x = pack2(n0.x, n0.y); u.y = pack2(n0.z, n0.w);
      u.z = pack2(n1.x, n1.y); u.w = pack2(n1.z, n1.w);
      A4[cur ^ 1][ui] = u;
    }
    n0 = m0; n1 = m1;
    __syncthreads();
  }

  // ---- epilogue: acc -> hp, then LN + GELU (verbatim pv_v5b)
  #pragma unroll
  for (int q = 0; q < 4; ++q) hp[kg * 4 + q][ch] = acc0[q] + acc1[q];
  __syncthreads();

  const int row = t >> 5;
  const int c0  = t & 31;
  float v[4], s = 0.f, sq = 0.f;
  #pragma unroll
  for (int e = 0; e < 4; ++e) {
    v[e] = hp[row][c0 + e * 32];
    s += v[e]; sq += v[e] * v[e];
  }
  #pragma unroll
  for (int off = 16; off; off >>= 1) { s += __shfl_xor(s, off); sq += __shfl_xor(sq, off); }
  const float mu  = s  * (1.f / 128.f);
  const float var = sq * (1.f / 128.f) - mu * mu;
  const float inv = rsqrtf(var + EPS_);
  float* orow = out0 + ((size_t)(b * N_ + i0 + row)) * OUTF_;
  #pragma unroll
  for (int e = 0; e < 4; ++e) {
    const int chh = c0 + e * 32;
    float y = (v[e] - mu) * inv * gamma[chh] + beta[chh];
    y *= OUT_SCALE_;
    orow[chh] = 0.5f * y * (1.f + erff(y * 0.70710678118654752f));
  }
}

extern "C" void kernel_launch(void* const* d_in, const int* in_sizes, int n_in,
                              void* d_out, int out_size, void* d_ws, size_t ws_size,
                              hipStream_t stream) {
  (void)in_sizes; (void)n_in; (void)out_size; (void)ws_size;
  const float* h        = (const float*)d_in[0];
  const int*   adj      = (const int*)d_in[1];
  const float* W        = (const float*)d_in[2];
  const float* alp      = (const float*)d_in[3];
  const float* arp      = (const float*)d_in[4];
  const float* aln      = (const float*)d_in[5];
  const float* arn      = (const float*)d_in[6];
  const float* rel_emb  = (const float*)d_in[7];
  const float* a_rel_p  = (const float*)d_in[8];
  const float* a_rel_n  = (const float*)d_in[9];
  const float* ll1      = (const float*)d_in[10];
  const float* lr1      = (const float*)d_in[11];
  const float* ll2      = (const float*)d_in[12];
  const float* lr2      = (const float*)d_in[13];
  const float* gamma    = (const float*)d_in[14];
  const float* beta     = (const float*)d_in[15];

  float* out0 = (float*)d_out;                          // gelu(h'): B*N*OUTF
  float* out1 = out0 + (size_t)B_ * N_ * OUTF_;         // attention: B*N*N

  float* ws    = (float*)d_ws;
  float* scal  = ws;                    // 32 floats
  float* lposv = ws + 32;               // B*N
  float* rposv = lposv + B_ * N_;
  float* lnegv = rposv + B_ * N_;
  float* rnegv = lnegv + B_ * N_;
  unsigned short* WhvT = (unsigned short*)(rnegv + B_ * N_);   // [B][OUTF][N] bf16

  scalars_kernel<<<1, 64, 0, stream>>>(rel_emb, a_rel_p, a_rel_n, ll1, lr1, ll2, lr2, scal);
  wh_dots_kernel<<<(B_ * N_) / 16, 256, 0, stream>>>(h, W, alp, arp, aln, arn,
                                                     WhvT, lposv, rposv, lnegv, rnegv);
  attn_v4<<<(B_ * N_) / 8, 512, 0, stream>>>(adj, lposv, rposv, lnegv, rnegv, scal, out1);
  pv_v5c<<<B_ * (N_ / 16), 512, 0, stream>>>(out1, WhvT, gamma, beta, out0);
}